// Round 1
// baseline (255.674 us; speedup 1.0000x reference)
//
#include <hip/hip_runtime.h>
#include <cmath>

// Problem constants (fixed instantiation): x is [B, D] float32.
constexpr int B = 256;
constexpr int D = 512;
constexpr int ROW = D + D * D + D;          // 263168 floats per output row
constexpr int PAIR_ROWS_PER_BLOCK = 32;     // 32 rows x 128 float4-cols per block
constexpr int PAIR_BLOCKS = D / PAIR_ROWS_PER_BLOCK;  // 16
constexpr int BLOCKS_PER_BATCH = PAIR_BLOCKS + 1;     // +1 for sin+identity

__global__ __launch_bounds__(256)
void basis_expansion_kernel(const float* __restrict__ x, float* __restrict__ out) {
    const int bid  = blockIdx.x;
    const int b    = bid / BLOCKS_PER_BATCH;
    const int part = bid % BLOCKS_PER_BATCH;
    const int t    = threadIdx.x;

    const float* xrow = x + b * D;
    float* orow = out + (size_t)b * ROW;

    __shared__ float sx[D];
    sx[t]       = xrow[t];
    sx[t + 256] = xrow[t + 256];
    __syncthreads();

    // Every thread owns one fixed float4 of the x row (column direction).
    const int col4 = t & 127;                 // 128 float4s cover D=512
    const float4 v = reinterpret_cast<const float4*>(sx)[col4];

    if (part == PAIR_BLOCKS) {
        // sin section (threads 0..127) + identity section (threads 128..255)
        if (t < 128) {
            float4 s;
            s.x = sinf(v.x); s.y = sinf(v.y); s.z = sinf(v.z); s.w = sinf(v.w);
            reinterpret_cast<float4*>(orow)[col4] = s;
        } else {
            reinterpret_cast<float4*>(orow + D + D * D)[col4] = v;
        }
        return;
    }

    // Pair section: out[b, D + i*D + j] = x[b,i] * x[b,j]
    // This block covers rows [part*32, part*32+32). Per iteration m, threads
    // 0..127 handle row 2m (cols 0..511 as float4), threads 128..255 row 2m+1.
    const int row0 = part * PAIR_ROWS_PER_BLOCK + (t >> 7);
    float4* pbase = reinterpret_cast<float4*>(orow + D);  // 16B aligned (512 % 4 == 0)

#pragma unroll
    for (int m = 0; m < PAIR_ROWS_PER_BLOCK / 2; ++m) {
        const int row = row0 + 2 * m;
        const float a = sx[row];              // LDS broadcast (conflict-free)
        float4 w;
        w.x = a * v.x; w.y = a * v.y; w.z = a * v.z; w.w = a * v.w;
        pbase[row * 128 + col4] = w;          // global_store_dwordx4, coalesced
    }
}

extern "C" void kernel_launch(void* const* d_in, const int* in_sizes, int n_in,
                              void* d_out, int out_size, void* d_ws, size_t ws_size,
                              hipStream_t stream) {
    const float* x = (const float*)d_in[0];
    float* out = (float*)d_out;
    dim3 grid(B * BLOCKS_PER_BATCH);
    dim3 block(256);
    basis_expansion_kernel<<<grid, block, 0, stream>>>(x, out);
}